// Round 14
// baseline (592.624 us; speedup 1.0000x reference)
//
#include <hip/hip_runtime.h>
#include <math.h>

#define N_NODES 50000
#define E_EDGES 600000
#define D_DIM 128
#define OUT_DIM 40
#define N_ITERS 5
#define GAMMA_C 0.1f
#define EPS_C 0.1f
#define SCAN_BLOCKS 196          // 196*256 = 50176 >= N_NODES
#define GEMM_BLOCKS 391          // ceil(50000/128)
#define EDGE_BLOCKS 2344         // ceil(600000/256)
#define DEG_BINS 64

typedef short v8s __attribute__((ext_vector_type(8)));   // 8 bf16 (4 VGPRs)
typedef float v4f __attribute__((ext_vector_type(4)));   // MFMA accumulator
typedef unsigned int uint;
typedef unsigned short ushort;

__device__ __forceinline__ ushort f2bf(float f) {        // RNE fp32->bf16
    union { float f; uint u; } v; v.f = f;
    uint u = v.u;
    uint r = 0x7fffu + ((u >> 16) & 1u);
    return (ushort)((u + r) >> 16);
}
__device__ __forceinline__ float bf2f(ushort h) {
    union { uint u; float f; } v; v.u = ((uint)h) << 16;
    return v.f;
}
__device__ __forceinline__ float bflo(uint u) {
    union { uint u; float f; } v; v.u = u << 16; return v.f;
}
__device__ __forceinline__ float bfhi(uint u) {
    union { uint u; float f; } v; v.u = u & 0xffff0000u; return v.f;
}

// ---------------------------------------------------------------------------
// Combined (once): zero cursor[N] + deg bins + weight prep to bf16.
// Wcat2[c][k] (row-stride 256): k<128 -> A[c][k]=Wanti[c][k]-Wanti[k][c]-g*I,
//                               k>=128 -> W_lin[c][k-128]
// WoutH: 48x128 bf16 (rows 40..47 zero-padded)
// ---------------------------------------------------------------------------
__global__ __launch_bounds__(256) void zero_prep_kernel(int* __restrict__ cursor,
                                                        int* __restrict__ bins,
                                                        const float* __restrict__ Wemb,
                                                        const float* __restrict__ Wlin,
                                                        const float* __restrict__ Wanti,
                                                        const float* __restrict__ Wout,
                                                        ushort* __restrict__ WembH,
                                                        ushort* __restrict__ Wcat2H,
                                                        ushort* __restrict__ WoutH) {
    int i = blockIdx.x * 256 + threadIdx.x;
    if (i < N_NODES) cursor[i] = 0;
    if (i < DEG_BINS) bins[i] = 0;
    if (i < D_DIM * D_DIM) {
        int r = i >> 7, c = i & 127;
        WembH[i] = f2bf(Wemb[i]);
        float a = Wanti[r * 128 + c] - Wanti[c * 128 + r];
        if (r == c) a -= GAMMA_C;
        Wcat2H[r * 256 + c]       = f2bf(a);
        Wcat2H[r * 256 + 128 + c] = f2bf(Wlin[r * 128 + c]);
        if (i < 48 * 128) WoutH[i] = (r < OUT_DIM) ? f2bf(Wout[r * 128 + c]) : (ushort)0;
    }
}

// ---------------------------------------------------------------------------
// MERGED: embed GEMM (blocks [0,391)) + CSR build scatter (blocks [391,2735)).
// embed: xh = bf16(x0 @ W_emb^T + b_emb); hybrid LDS (A staged, W global).
// build: es2[pos] = {src, bits(w)} at pos = cursor[dst]++ (one 8B store/edge).
// Fragments (verified m89/m120): A[m=lane&15][k=quad*8+j],
// B[n=lane&15][k=quad*8+j], C/D: col=lane&15, row=quad*4+reg.
// ---------------------------------------------------------------------------
__global__ __launch_bounds__(256) void build_embed_kernel(
        const float* __restrict__ Xf, const ushort* __restrict__ Wh,
        const float* __restrict__ bias, ushort* __restrict__ xH,
        const int* __restrict__ src, const int* __restrict__ dst,
        const float* __restrict__ ew, int* __restrict__ cursor,
        int2* __restrict__ es2, int M) {
    __shared__ ushort Xs[128 * 128];          // 32 KB (embed blocks only)
    const int tid = threadIdx.x;

    if (blockIdx.x >= GEMM_BLOCKS) {
        // ---- build role ----
        int e = (blockIdx.x - GEMM_BLOCKS) * 256 + tid;
        if (e < E_EDGES) {
            int d = dst[e];
            int pos = atomicAdd(&cursor[d], 1);
            es2[pos] = make_int2(src[e], __float_as_int(ew[e]));
        }
        return;
    }

    // ---- embed role ----
    const int rowBase = blockIdx.x * 128;
#pragma unroll
    for (int p = 0; p < 8; ++p) {
        int cid = p * 256 + tid;
        int r = cid >> 4, c8 = cid & 15;
        int gr = rowBase + r;
        uint4 val = make_uint4(0, 0, 0, 0);
        if (gr < M) {
            const float* ptr = Xf + (size_t)gr * 128 + c8 * 8;
            float4 f0 = *(const float4*)ptr;
            float4 f1 = *(const float4*)(ptr + 4);
            val.x = (uint)f2bf(f0.x) | ((uint)f2bf(f0.y) << 16);
            val.y = (uint)f2bf(f0.z) | ((uint)f2bf(f0.w) << 16);
            val.z = (uint)f2bf(f1.x) | ((uint)f2bf(f1.y) << 16);
            val.w = (uint)f2bf(f1.z) | ((uint)f2bf(f1.w) << 16);
        }
        *(uint4*)(Xs + r * 128 + ((c8 ^ (r & 7)) << 3)) = val;
    }
    __syncthreads();

    const int lane = tid & 63;
    const int wv = tid >> 6;
    const int wrow = (wv & 1) * 64;
    const int wcol = (wv >> 1) * 64;
    const int l16 = lane & 15;
    const int q = lane >> 4;

    v4f acc[4][4];
#pragma unroll
    for (int i = 0; i < 4; ++i)
#pragma unroll
        for (int j = 0; j < 4; ++j) { v4f z = {0.f,0.f,0.f,0.f}; acc[i][j] = z; }

#pragma unroll
    for (int ks = 0; ks < 4; ++ks) {
        const int chunk = ks * 4 + q;
        v8s a[4], b[4];
#pragma unroll
        for (int i = 0; i < 4; ++i) {
            int m = wrow + i * 16 + l16;
            a[i] = *(const v8s*)(Xs + m * 128 + ((chunk ^ (m & 7)) << 3));
        }
#pragma unroll
        for (int j = 0; j < 4; ++j)
            b[j] = *(const v8s*)(Wh + (size_t)(wcol + j * 16 + l16) * 128 + chunk * 8);
#pragma unroll
        for (int i = 0; i < 4; ++i)
#pragma unroll
            for (int j = 0; j < 4; ++j)
                acc[i][j] = __builtin_amdgcn_mfma_f32_16x16x32_bf16(a[i], b[j], acc[i][j], 0, 0, 0);
    }

#pragma unroll
    for (int j = 0; j < 4; ++j) {
        int col = wcol + j * 16 + l16;
        float bj = bias[col];
#pragma unroll
        for (int i = 0; i < 4; ++i) {
            int grB = rowBase + wrow + i * 16 + q * 4;
#pragma unroll
            for (int r = 0; r < 4; ++r) {
                int gr = grB + r;
                if (gr < M) xH[(size_t)gr * 128 + col] = f2bf(acc[i][j][r] + bj);
            }
        }
    }
}

// ---------------------------------------------------------------------------
// conv GEMM + update (R12 structure — best: 128-row tile, 64x64 microtiles,
// BOTH K-chunks staged up front into two LDS buffers, ONE barrier):
//   Xs0 = aggxh rows, Xs1 = xh rows (2 x 32 KB),
//   conv = aggxh@W_lin^T + xh@A^T + b_conv
//   xh  += bf16( eps*tanh(conv) )            (x-old read from Xs1)
// doOut (last iter): write xh_new into Xs1, sync, out = xh_new@Wout^T + b_out.
// ---------------------------------------------------------------------------
__global__ __launch_bounds__(256) void mfma_conv_update(
        ushort* __restrict__ xh, const ushort* __restrict__ aggxh,
        const ushort* __restrict__ Wcat2, const float* __restrict__ bconv,
        const ushort* __restrict__ WoutH, const float* __restrict__ bout,
        float* __restrict__ out, int doOut, int M) {
    __shared__ ushort Xs0[128 * 128];         // aggxh tile (32 KB)
    __shared__ ushort Xs1[128 * 128];         // xh tile    (32 KB)
    const int tid = threadIdx.x;
    const int rowBase = blockIdx.x * 128;
    const int lane = tid & 63;
    const int wv = tid >> 6;
    const int wrow = (wv & 1) * 64;
    const int wcol = (wv >> 1) * 64;
    const int l16 = lane & 15;
    const int q = lane >> 4;

    // ---- stage both tiles, ONE barrier (all 16 loads in flight together) ----
#pragma unroll
    for (int p = 0; p < 16; ++p) {
        int cid = p * 256 + tid;              // 4096 uint4: [0,2048)=Xs0, rest Xs1
        int buf = cid >> 11;
        int idx = cid & 2047;
        int r = idx >> 4, c8 = idx & 15;
        int gr = rowBase + r;
        const ushort* srcp = buf ? xh : aggxh;
        ushort* dstp = buf ? Xs1 : Xs0;
        uint4 xv = make_uint4(0, 0, 0, 0);
        if (gr < M) xv = *(const uint4*)(srcp + (size_t)gr * 128 + c8 * 8);
        *(uint4*)(dstp + r * 128 + ((c8 ^ (r & 7)) << 3)) = xv;
    }
    __syncthreads();

    v4f acc[4][4];
#pragma unroll
    for (int i = 0; i < 4; ++i)
#pragma unroll
        for (int j = 0; j < 4; ++j) { v4f z = {0.f,0.f,0.f,0.f}; acc[i][j] = z; }

    // 8 K-chunks: ks<4 -> aggxh x W_lin (wOff=128); ks>=4 -> xh x A (wOff=0)
#pragma unroll
    for (int ks = 0; ks < 8; ++ks) {
        const ushort* Xsrc = (ks < 4) ? Xs0 : Xs1;
        const int wOff = (ks < 4) ? 128 : 0;
        const int chunk = (ks & 3) * 4 + q;
        v8s a[4], b[4];
#pragma unroll
        for (int i = 0; i < 4; ++i) {
            int m = wrow + i * 16 + l16;
            a[i] = *(const v8s*)(Xsrc + m * 128 + ((chunk ^ (m & 7)) << 3));
        }
#pragma unroll
        for (int j = 0; j < 4; ++j)
            b[j] = *(const v8s*)(Wcat2 + (size_t)(wcol + j * 16 + l16) * 256 + wOff + chunk * 8);
#pragma unroll
        for (int i = 0; i < 4; ++i)
#pragma unroll
            for (int j = 0; j < 4; ++j)
                acc[i][j] = __builtin_amdgcn_mfma_f32_16x16x32_bf16(a[i], b[j], acc[i][j], 0, 0, 0);
    }

    // ---- epilogue: x-old from Xs1 (this block's xh rows) ----
#pragma unroll
    for (int j = 0; j < 4; ++j) {
        int col = wcol + j * 16 + l16;
        float bj = bconv[col];
        const int csw = col >> 3, clo = col & 7;
#pragma unroll
        for (int i = 0; i < 4; ++i) {
            int trB = wrow + i * 16 + q * 4;
#pragma unroll
            for (int r = 0; r < 4; ++r) {
                int tr = trB + r;
                int gr = rowBase + tr;
                if (gr < M) {
                    int li = tr * 128 + (((csw ^ (tr & 7)) << 3) | clo);
                    float conv = acc[i][j][r] + bj;
                    float xv = bf2f(Xs1[li]) + EPS_C * tanhf(conv);
                    ushort h = f2bf(xv);
                    xh[(size_t)gr * 128 + col] = h;
                    if (doOut) Xs1[li] = h;   // refresh tile for fused readout
                }
            }
        }
    }

    if (doOut) {
        __syncthreads();                      // Xs1 now holds xh_new
        // out phase: waves take row-quarters (32 rows each), 48 padded cols
        v4f acc2[2][3];
#pragma unroll
        for (int i = 0; i < 2; ++i)
#pragma unroll
            for (int j = 0; j < 3; ++j) { v4f z = {0.f,0.f,0.f,0.f}; acc2[i][j] = z; }

#pragma unroll
        for (int ks = 0; ks < 4; ++ks) {
            const int chunk = ks * 4 + q;
            v8s a2[2], b2[3];
#pragma unroll
            for (int i = 0; i < 2; ++i) {
                int m = wv * 32 + i * 16 + l16;
                a2[i] = *(const v8s*)(Xs1 + m * 128 + ((chunk ^ (m & 7)) << 3));
            }
#pragma unroll
            for (int j = 0; j < 3; ++j)
                b2[j] = *(const v8s*)(WoutH + (size_t)(j * 16 + l16) * 128 + chunk * 8);
#pragma unroll
            for (int i = 0; i < 2; ++i)
#pragma unroll
                for (int j = 0; j < 3; ++j)
                    acc2[i][j] = __builtin_amdgcn_mfma_f32_16x16x32_bf16(a2[i], b2[j], acc2[i][j], 0, 0, 0);
        }

#pragma unroll
        for (int j = 0; j < 3; ++j) {
            int col = j * 16 + l16;
            if (col >= OUT_DIM) continue;
            float bj = bout[col];
#pragma unroll
            for (int i = 0; i < 2; ++i) {
                int grB = rowBase + wv * 32 + i * 16 + q * 4;
#pragma unroll
                for (int r = 0; r < 4; ++r) {
                    int gr = grB + r;
                    if (gr < M) out[(size_t)gr * OUT_DIM + col] = acc2[i][j][r] + bj;
                }
            }
        }
    }
}

// ---------------------------------------------------------------------------
// CSR build (once per launch; edge structure is iteration-invariant)
// ---------------------------------------------------------------------------
__global__ __launch_bounds__(256) void hist_kernel(const int* __restrict__ dst,
                                                   int* __restrict__ cnt) {
    int e = blockIdx.x * 256 + threadIdx.x;
    if (e < E_EDGES) atomicAdd(&cnt[dst[e]], 1);
}

__global__ __launch_bounds__(256) void scan_phase1(const int* __restrict__ deg,
                                                   int* __restrict__ localEx,
                                                   int* __restrict__ blockSums,
                                                   int* __restrict__ degArr) {
    __shared__ int tmp[256];
    const int t = threadIdx.x;
    const int i = blockIdx.x * 256 + t;
    int v = (i < N_NODES) ? deg[i] : 0;
    if (i < N_NODES) degArr[i] = v;           // save degree for the sort
    tmp[t] = v;
    __syncthreads();
#pragma unroll
    for (int off = 1; off < 256; off <<= 1) {
        int u = (t >= off) ? tmp[t - off] : 0;
        __syncthreads();
        tmp[t] += u;
        __syncthreads();
    }
    if (i < N_NODES) localEx[i] = tmp[t] - v;
    if (t == 255) blockSums[blockIdx.x] = tmp[255];
}

// merged phase2+3: every block redundantly scans the 196 block sums (read-only),
// picks its own exclusive offset, finalizes rowStart + cursor.
__global__ __launch_bounds__(256) void scan_phase23(int* __restrict__ rowStart,
                                                    const int* __restrict__ blockSums,
                                                    int* __restrict__ cursor) {
    __shared__ int tmp[256];
    __shared__ int offs;
    const int t = threadIdx.x;
    int v = (t < SCAN_BLOCKS) ? blockSums[t] : 0;
    tmp[t] = v;
    __syncthreads();
#pragma unroll
    for (int off = 1; off < 256; off <<= 1) {
        int u = (t >= off) ? tmp[t - off] : 0;
        __syncthreads();
        tmp[t] += u;
        __syncthreads();
    }
    if (t == blockIdx.x) offs = tmp[t] - v;
    __syncthreads();
    const int i = blockIdx.x * 256 + t;
    if (i < N_NODES) {
        int val = rowStart[i] + offs;
        rowStart[i] = val;
        cursor[i] = val;
    }
}

// ---------------------------------------------------------------------------
// Degree counting sort (once): perm = node IDs ordered by degree, so each
// gather wave handles 4 near-equal-degree nodes (kills divergence tail).
// ---------------------------------------------------------------------------
__global__ __launch_bounds__(256) void degsort_hist(const int* __restrict__ degArr,
                                                    int* __restrict__ bins) {
    __shared__ int lb[DEG_BINS];
    const int t = threadIdx.x;
    if (t < DEG_BINS) lb[t] = 0;
    __syncthreads();
    int i = blockIdx.x * 256 + t;
    if (i < N_NODES) {
        int d = degArr[i]; if (d > DEG_BINS - 1) d = DEG_BINS - 1;
        atomicAdd(&lb[d], 1);
    }
    __syncthreads();
    if (t < DEG_BINS && lb[t]) atomicAdd(&bins[t], lb[t]);
}

__global__ __launch_bounds__(64) void degsort_scan(const int* __restrict__ bins,
                                                   int* __restrict__ binCursor) {
    __shared__ int tmp[DEG_BINS];
    const int t = threadIdx.x;
    int v = bins[t];
    tmp[t] = v;
    __syncthreads();
#pragma unroll
    for (int off = 1; off < DEG_BINS; off <<= 1) {
        int u = (t >= off) ? tmp[t - off] : 0;
        __syncthreads();
        tmp[t] += u;
        __syncthreads();
    }
    binCursor[t] = tmp[t] - v;                // exclusive offsets
}

__global__ __launch_bounds__(256) void degsort_scatter(const int* __restrict__ degArr,
                                                       int* __restrict__ binCursor,
                                                       int* __restrict__ perm) {
    int i = blockIdx.x * 256 + threadIdx.x;
    if (i >= N_NODES) return;
    int d = degArr[i]; if (d > DEG_BINS - 1) d = DEG_BINS - 1;
    int pos = atomicAdd(&binCursor[d], 1);
    perm[pos] = i;
}

// ---------------------------------------------------------------------------
// Gather raw x: aggxh[n] = bf16( sum_e w_e * xh[src_e] ), nodes visited in
// degree-sorted order (perm) so the 4 nodes per wave have equal-length loops.
// 16 lanes/node (16 B/lane), unroll-4 -> 16 independent load chains/wave.
// ---------------------------------------------------------------------------
__global__ __launch_bounds__(256) void gather_x_kernel(
        const ushort* __restrict__ xh, const int2* __restrict__ es2,
        const int* __restrict__ rowStart, const int* __restrict__ rowEnd,
        const int* __restrict__ perm, ushort* __restrict__ aggxh) {
    int gid = blockIdx.x * 256 + threadIdx.x;
    int slot = gid >> 4;
    if (slot >= N_NODES) return;
    int node = perm[slot];
    int q = gid & 15;                     // elems [q*8, q*8+8)
    int e = rowStart[node], end = rowEnd[node];

    float sA[8] = {0,0,0,0,0,0,0,0};
    float sB[8] = {0,0,0,0,0,0,0,0};
    for (; e + 4 <= end; e += 4) {
        int2 m0 = es2[e], m1 = es2[e + 1], m2 = es2[e + 2], m3 = es2[e + 3];
        uint4 v0 = *(const uint4*)(xh + (size_t)m0.x * 128 + q * 8);
        uint4 v1 = *(const uint4*)(xh + (size_t)m1.x * 128 + q * 8);
        uint4 v2 = *(const uint4*)(xh + (size_t)m2.x * 128 + q * 8);
        uint4 v3 = *(const uint4*)(xh + (size_t)m3.x * 128 + q * 8);
        float w0 = __int_as_float(m0.y), w1 = __int_as_float(m1.y);
        float w2 = __int_as_float(m2.y), w3 = __int_as_float(m3.y);
        sA[0] = fmaf(w0, bflo(v0.x), sA[0]); sA[1] = fmaf(w0, bfhi(v0.x), sA[1]);
        sA[2] = fmaf(w0, bflo(v0.y), sA[2]); sA[3] = fmaf(w0, bfhi(v0.y), sA[3]);
        sA[4] = fmaf(w0, bflo(v0.z), sA[4]); sA[5] = fmaf(w0, bfhi(v0.z), sA[5]);
        sA[6] = fmaf(w0, bflo(v0.w), sA[6]); sA[7] = fmaf(w0, bfhi(v0.w), sA[7]);
        sB[0] = fmaf(w1, bflo(v1.x), sB[0]); sB[1] = fmaf(w1, bfhi(v1.x), sB[1]);
        sB[2] = fmaf(w1, bflo(v1.y), sB[2]); sB[3] = fmaf(w1, bfhi(v1.y), sB[3]);
        sB[4] = fmaf(w1, bflo(v1.z), sB[4]); sB[5] = fmaf(w1, bfhi(v1.z), sB[5]);
        sB[6] = fmaf(w1, bflo(v1.w), sB[6]); sB[7] = fmaf(w1, bfhi(v1.w), sB[7]);
        sA[0] = fmaf(w2, bflo(v2.x), sA[0]); sA[1] = fmaf(w2, bfhi(v2.x), sA[1]);
        sA[2] = fmaf(w2, bflo(v2.y), sA[2]); sA[3] = fmaf(w2, bfhi(v2.y), sA[3]);
        sA[4] = fmaf(w2, bflo(v2.z), sA[4]); sA[5] = fmaf(w2, bfhi(v2.z), sA[5]);
        sA[6] = fmaf(w2, bflo(v2.w), sA[6]); sA[7] = fmaf(w2, bfhi(v2.w), sA[7]);
        sB[0] = fmaf(w3, bflo(v3.x), sB[0]); sB[1] = fmaf(w3, bfhi(v3.x), sB[1]);
        sB[2] = fmaf(w3, bflo(v3.y), sB[2]); sB[3] = fmaf(w3, bfhi(v3.y), sB[3]);
        sB[4] = fmaf(w3, bflo(v3.z), sB[4]); sB[5] = fmaf(w3, bfhi(v3.z), sB[5]);
        sB[6] = fmaf(w3, bflo(v3.w), sB[6]); sB[7] = fmaf(w3, bfhi(v3.w), sB[7]);
    }
    for (; e < end; ++e) {
        int2 m = es2[e];
        float w = __int_as_float(m.y);
        uint4 v = *(const uint4*)(xh + (size_t)m.x * 128 + q * 8);
        sA[0] = fmaf(w, bflo(v.x), sA[0]); sA[1] = fmaf(w, bfhi(v.x), sA[1]);
        sA[2] = fmaf(w, bflo(v.y), sA[2]); sA[3] = fmaf(w, bfhi(v.y), sA[3]);
        sA[4] = fmaf(w, bflo(v.z), sA[4]); sA[5] = fmaf(w, bfhi(v.z), sA[5]);
        sA[6] = fmaf(w, bflo(v.w), sA[6]); sA[7] = fmaf(w, bfhi(v.w), sA[7]);
    }
    uint4 o;
    o.x = (uint)f2bf(sA[0] + sB[0]) | ((uint)f2bf(sA[1] + sB[1]) << 16);
    o.y = (uint)f2bf(sA[2] + sB[2]) | ((uint)f2bf(sA[3] + sB[3]) << 16);
    o.z = (uint)f2bf(sA[4] + sB[4]) | ((uint)f2bf(sA[5] + sB[5]) << 16);
    o.w = (uint)f2bf(sA[6] + sB[6]) | ((uint)f2bf(sA[7] + sB[7]) << 16);
    *(uint4*)(aggxh + (size_t)node * 128 + q * 8) = o;
}

extern "C" void kernel_launch(void* const* d_in, const int* in_sizes, int n_in,
                              void* d_out, int out_size, void* d_ws, size_t ws_size,
                              hipStream_t stream) {
    const float* x_in   = (const float*)d_in[0];
    const int*   ei     = (const int*)  d_in[1];   // (2,E) int32: src=ei, dst=ei+E
    const float* ew     = (const float*)d_in[2];
    const float* W_emb  = (const float*)d_in[3];
    const float* b_emb  = (const float*)d_in[4];
    const float* W_lin  = (const float*)d_in[5];
    const float* W_anti = (const float*)d_in[6];
    const float* b_conv = (const float*)d_in[7];
    const float* W_out  = (const float*)d_in[8];
    const float* b_out  = (const float*)d_in[9];
    float* out = (float*)d_out;

    // workspace: xh | aggxh (bf16) | WembH | Wcat2H | WoutH | rowStart |
    //            cursor | es2(int2) | blockSums | degArr | perm | bins |
    //            binCursor    (~32 MB)
    ushort* xh     = (ushort*)d_ws;
    ushort* aggxh  = xh + (size_t)N_NODES * D_DIM;
    ushort* WembH  = aggxh + (size_t)N_NODES * D_DIM;
    ushort* Wcat2H = WembH + D_DIM * D_DIM;
    ushort* WoutH  = Wcat2H + 2 * D_DIM * D_DIM;
    int*    rowStart = (int*)(WoutH + 48 * D_DIM);
    int*    cursor   = rowStart + N_NODES;
    int2*   es2      = (int2*)(cursor + N_NODES);
    int*    blockSums = (int*)(es2 + E_EDGES);
    int*    degArr    = blockSums + SCAN_BLOCKS;
    int*    perm      = degArr + N_NODES;
    int*    bins      = perm + N_NODES;
    int*    binCursor = bins + DEG_BINS;

    const int* src = ei;
    const int* dst = ei + E_EDGES;

    // ---- CSR chain + weight prep ----
    zero_prep_kernel<<<SCAN_BLOCKS, 256, 0, stream>>>(cursor, bins, W_emb, W_lin,
                                                      W_anti, W_out, WembH, Wcat2H, WoutH);
    hist_kernel<<<EDGE_BLOCKS, 256, 0, stream>>>(dst, cursor);
    scan_phase1<<<SCAN_BLOCKS, 256, 0, stream>>>(cursor, rowStart, blockSums, degArr);
    scan_phase23<<<SCAN_BLOCKS, 256, 0, stream>>>(rowStart, blockSums, cursor);
    // ---- degree counting sort (once) ----
    degsort_hist<<<SCAN_BLOCKS, 256, 0, stream>>>(degArr, bins);
    degsort_scan<<<1, DEG_BINS, 0, stream>>>(bins, binCursor);
    degsort_scatter<<<SCAN_BLOCKS, 256, 0, stream>>>(degArr, binCursor, perm);
    // ---- build (CSR scatter) + embed GEMM, role-split & overlapped ----
    build_embed_kernel<<<GEMM_BLOCKS + EDGE_BLOCKS, 256, 0, stream>>>(
        x_in, WembH, b_emb, xh, src, dst, ew, cursor, es2, N_NODES);
    // after build: cursor[d] == row end offset

    // ---- iterations: gather (degree-sorted) + conv GEMM; last conv fuses
    //      the readout ----
    for (int it = 0; it < N_ITERS; ++it) {
        gather_x_kernel<<<(N_NODES * 16 + 255) / 256, 256, 0, stream>>>(
            xh, es2, rowStart, cursor, perm, aggxh);
        mfma_conv_update<<<GEMM_BLOCKS, 256, 0, stream>>>(
            xh, aggxh, Wcat2H, b_conv, WoutH, b_out, out,
            (it == N_ITERS - 1) ? 1 : 0, N_NODES);
    }
}

// Round 15
// 438.021 us; speedup vs baseline: 1.3530x; 1.3530x over previous
//
#include <hip/hip_runtime.h>
#include <math.h>

#define N_NODES 50000
#define E_EDGES 600000
#define D_DIM 128
#define OUT_DIM 40
#define N_ITERS 5
#define GAMMA_C 0.1f
#define EPS_C 0.1f
#define SCAN_BLOCKS 196          // 196*256 = 50176 >= N_NODES
#define GEMM_BLOCKS 391          // ceil(50000/128)
#define EDGE_BLOCKS 2344         // ceil(600000/256)

typedef short v8s __attribute__((ext_vector_type(8)));   // 8 bf16 (4 VGPRs)
typedef float v4f __attribute__((ext_vector_type(4)));   // MFMA accumulator
typedef unsigned int uint;
typedef unsigned short ushort;

__device__ __forceinline__ ushort f2bf(float f) {        // RNE fp32->bf16
    union { float f; uint u; } v; v.f = f;
    uint u = v.u;
    uint r = 0x7fffu + ((u >> 16) & 1u);
    return (ushort)((u + r) >> 16);
}
__device__ __forceinline__ float bf2f(ushort h) {
    union { uint u; float f; } v; v.u = ((uint)h) << 16;
    return v.f;
}
__device__ __forceinline__ float bflo(uint u) {
    union { uint u; float f; } v; v.u = u << 16; return v.f;
}
__device__ __forceinline__ float bfhi(uint u) {
    union { uint u; float f; } v; v.u = u & 0xffff0000u; return v.f;
}

// ---------------------------------------------------------------------------
// Combined (once): zero cursor[N] + weight prep to bf16.
// Wcat2[c][k] (row-stride 256): k<128 -> A[c][k]=Wanti[c][k]-Wanti[k][c]-g*I,
//                               k>=128 -> W_lin[c][k-128]
// WoutH: 48x128 bf16 (rows 40..47 zero-padded)
// ---------------------------------------------------------------------------
__global__ __launch_bounds__(256) void zero_prep_kernel(int* __restrict__ cursor,
                                                        const float* __restrict__ Wemb,
                                                        const float* __restrict__ Wlin,
                                                        const float* __restrict__ Wanti,
                                                        const float* __restrict__ Wout,
                                                        ushort* __restrict__ WembH,
                                                        ushort* __restrict__ Wcat2H,
                                                        ushort* __restrict__ WoutH) {
    int i = blockIdx.x * 256 + threadIdx.x;
    if (i < N_NODES) cursor[i] = 0;
    if (i < D_DIM * D_DIM) {
        int r = i >> 7, c = i & 127;
        WembH[i] = f2bf(Wemb[i]);
        float a = Wanti[r * 128 + c] - Wanti[c * 128 + r];
        if (r == c) a -= GAMMA_C;
        Wcat2H[r * 256 + c]       = f2bf(a);
        Wcat2H[r * 256 + 128 + c] = f2bf(Wlin[r * 128 + c]);
        if (i < 48 * 128) WoutH[i] = (r < OUT_DIM) ? f2bf(Wout[r * 128 + c]) : (ushort)0;
    }
}

// ---------------------------------------------------------------------------
// MERGED: embed GEMM (blocks [0,391)) + CSR build scatter (blocks [391,2735)).
// embed: xh = bf16(x0 @ W_emb^T + b_emb); hybrid LDS (A staged, W global).
// build: es2[pos] = {src, bits(w)} at pos = cursor[dst]++ (one 8B store/edge).
// Fragments (verified m89/m120): A[m=lane&15][k=quad*8+j],
// B[n=lane&15][k=quad*8+j], C/D: col=lane&15, row=quad*4+reg.
// ---------------------------------------------------------------------------
__global__ __launch_bounds__(256) void build_embed_kernel(
        const float* __restrict__ Xf, const ushort* __restrict__ Wh,
        const float* __restrict__ bias, ushort* __restrict__ xH,
        const int* __restrict__ src, const int* __restrict__ dst,
        const float* __restrict__ ew, int* __restrict__ cursor,
        int2* __restrict__ es2, int M) {
    __shared__ ushort Xs[128 * 128];          // 32 KB (embed blocks only)
    const int tid = threadIdx.x;

    if (blockIdx.x >= GEMM_BLOCKS) {
        // ---- build role ----
        int e = (blockIdx.x - GEMM_BLOCKS) * 256 + tid;
        if (e < E_EDGES) {
            int d = dst[e];
            int pos = atomicAdd(&cursor[d], 1);
            es2[pos] = make_int2(src[e], __float_as_int(ew[e]));
        }
        return;
    }

    // ---- embed role ----
    const int rowBase = blockIdx.x * 128;
#pragma unroll
    for (int p = 0; p < 8; ++p) {
        int cid = p * 256 + tid;
        int r = cid >> 4, c8 = cid & 15;
        int gr = rowBase + r;
        uint4 val = make_uint4(0, 0, 0, 0);
        if (gr < M) {
            const float* ptr = Xf + (size_t)gr * 128 + c8 * 8;
            float4 f0 = *(const float4*)ptr;
            float4 f1 = *(const float4*)(ptr + 4);
            val.x = (uint)f2bf(f0.x) | ((uint)f2bf(f0.y) << 16);
            val.y = (uint)f2bf(f0.z) | ((uint)f2bf(f0.w) << 16);
            val.z = (uint)f2bf(f1.x) | ((uint)f2bf(f1.y) << 16);
            val.w = (uint)f2bf(f1.z) | ((uint)f2bf(f1.w) << 16);
        }
        *(uint4*)(Xs + r * 128 + ((c8 ^ (r & 7)) << 3)) = val;
    }
    __syncthreads();

    const int lane = tid & 63;
    const int wv = tid >> 6;
    const int wrow = (wv & 1) * 64;
    const int wcol = (wv >> 1) * 64;
    const int l16 = lane & 15;
    const int q = lane >> 4;

    v4f acc[4][4];
#pragma unroll
    for (int i = 0; i < 4; ++i)
#pragma unroll
        for (int j = 0; j < 4; ++j) { v4f z = {0.f,0.f,0.f,0.f}; acc[i][j] = z; }

#pragma unroll
    for (int ks = 0; ks < 4; ++ks) {
        const int chunk = ks * 4 + q;
        v8s a[4], b[4];
#pragma unroll
        for (int i = 0; i < 4; ++i) {
            int m = wrow + i * 16 + l16;
            a[i] = *(const v8s*)(Xs + m * 128 + ((chunk ^ (m & 7)) << 3));
        }
#pragma unroll
        for (int j = 0; j < 4; ++j)
            b[j] = *(const v8s*)(Wh + (size_t)(wcol + j * 16 + l16) * 128 + chunk * 8);
#pragma unroll
        for (int i = 0; i < 4; ++i)
#pragma unroll
            for (int j = 0; j < 4; ++j)
                acc[i][j] = __builtin_amdgcn_mfma_f32_16x16x32_bf16(a[i], b[j], acc[i][j], 0, 0, 0);
    }

#pragma unroll
    for (int j = 0; j < 4; ++j) {
        int col = wcol + j * 16 + l16;
        float bj = bias[col];
#pragma unroll
        for (int i = 0; i < 4; ++i) {
            int grB = rowBase + wrow + i * 16 + q * 4;
#pragma unroll
            for (int r = 0; r < 4; ++r) {
                int gr = grB + r;
                if (gr < M) xH[(size_t)gr * 128 + col] = f2bf(acc[i][j][r] + bj);
            }
        }
    }
}

// ---------------------------------------------------------------------------
// conv GEMM + update (best structure: 128-row tile, 64x64 wave microtiles,
// BOTH K-chunks staged up front into two LDS buffers, ONE barrier):
//   Xs0 = aggxh rows, Xs1 = xh rows (2 x 32 KB),
//   conv = aggxh@W_lin^T + xh@A^T + b_conv   (fixed accumulation order)
//   xh  += bf16( eps*tanh(conv) )            (x-old read from Xs1)
// doOut (last iter): write xh_new into Xs1, sync, out = xh_new@Wout^T + b_out.
// ---------------------------------------------------------------------------
__global__ __launch_bounds__(256) void mfma_conv_update(
        ushort* __restrict__ xh, const ushort* __restrict__ aggxh,
        const ushort* __restrict__ Wcat2, const float* __restrict__ bconv,
        const ushort* __restrict__ WoutH, const float* __restrict__ bout,
        float* __restrict__ out, int doOut, int M) {
    __shared__ ushort Xs0[128 * 128];         // aggxh tile (32 KB)
    __shared__ ushort Xs1[128 * 128];         // xh tile    (32 KB)
    const int tid = threadIdx.x;
    const int rowBase = blockIdx.x * 128;
    const int lane = tid & 63;
    const int wv = tid >> 6;
    const int wrow = (wv & 1) * 64;
    const int wcol = (wv >> 1) * 64;
    const int l16 = lane & 15;
    const int q = lane >> 4;

    // ---- stage both tiles, ONE barrier (all 16 loads in flight together) ----
#pragma unroll
    for (int p = 0; p < 16; ++p) {
        int cid = p * 256 + tid;              // 4096 uint4: [0,2048)=Xs0, rest Xs1
        int buf = cid >> 11;
        int idx = cid & 2047;
        int r = idx >> 4, c8 = idx & 15;
        int gr = rowBase + r;
        const ushort* srcp = buf ? xh : aggxh;
        ushort* dstp = buf ? Xs1 : Xs0;
        uint4 xv = make_uint4(0, 0, 0, 0);
        if (gr < M) xv = *(const uint4*)(srcp + (size_t)gr * 128 + c8 * 8);
        *(uint4*)(dstp + r * 128 + ((c8 ^ (r & 7)) << 3)) = xv;
    }
    __syncthreads();

    v4f acc[4][4];
#pragma unroll
    for (int i = 0; i < 4; ++i)
#pragma unroll
        for (int j = 0; j < 4; ++j) { v4f z = {0.f,0.f,0.f,0.f}; acc[i][j] = z; }

    // 8 K-chunks: ks<4 -> aggxh x W_lin (wOff=128); ks>=4 -> xh x A (wOff=0)
#pragma unroll
    for (int ks = 0; ks < 8; ++ks) {
        const ushort* Xsrc = (ks < 4) ? Xs0 : Xs1;
        const int wOff = (ks < 4) ? 128 : 0;
        const int chunk = (ks & 3) * 4 + q;
        v8s a[4], b[4];
#pragma unroll
        for (int i = 0; i < 4; ++i) {
            int m = wrow + i * 16 + l16;
            a[i] = *(const v8s*)(Xsrc + m * 128 + ((chunk ^ (m & 7)) << 3));
        }
#pragma unroll
        for (int j = 0; j < 4; ++j)
            b[j] = *(const v8s*)(Wcat2 + (size_t)(wcol + j * 16 + l16) * 256 + wOff + chunk * 8);
#pragma unroll
        for (int i = 0; i < 4; ++i)
#pragma unroll
            for (int j = 0; j < 4; ++j)
                acc[i][j] = __builtin_amdgcn_mfma_f32_16x16x32_bf16(a[i], b[j], acc[i][j], 0, 0, 0);
    }

    // ---- epilogue: x-old from Xs1 (this block's xh rows) ----
#pragma unroll
    for (int j = 0; j < 4; ++j) {
        int col = wcol + j * 16 + l16;
        float bj = bconv[col];
        const int csw = col >> 3, clo = col & 7;
#pragma unroll
        for (int i = 0; i < 4; ++i) {
            int trB = wrow + i * 16 + q * 4;
#pragma unroll
            for (int r = 0; r < 4; ++r) {
                int tr = trB + r;
                int gr = rowBase + tr;
                if (gr < M) {
                    int li = tr * 128 + (((csw ^ (tr & 7)) << 3) | clo);
                    float conv = acc[i][j][r] + bj;
                    float xv = bf2f(Xs1[li]) + EPS_C * tanhf(conv);
                    ushort h = f2bf(xv);
                    xh[(size_t)gr * 128 + col] = h;
                    if (doOut) Xs1[li] = h;   // refresh tile for fused readout
                }
            }
        }
    }

    if (doOut) {
        __syncthreads();                      // Xs1 now holds xh_new
        // out phase: waves take row-quarters (32 rows each), 48 padded cols
        v4f acc2[2][3];
#pragma unroll
        for (int i = 0; i < 2; ++i)
#pragma unroll
            for (int j = 0; j < 3; ++j) { v4f z = {0.f,0.f,0.f,0.f}; acc2[i][j] = z; }

#pragma unroll
        for (int ks = 0; ks < 4; ++ks) {
            const int chunk = ks * 4 + q;
            v8s a2[2], b2[3];
#pragma unroll
            for (int i = 0; i < 2; ++i) {
                int m = wv * 32 + i * 16 + l16;
                a2[i] = *(const v8s*)(Xs1 + m * 128 + ((chunk ^ (m & 7)) << 3));
            }
#pragma unroll
            for (int j = 0; j < 3; ++j)
                b2[j] = *(const v8s*)(WoutH + (size_t)(j * 16 + l16) * 128 + chunk * 8);
#pragma unroll
            for (int i = 0; i < 2; ++i)
#pragma unroll
                for (int j = 0; j < 3; ++j)
                    acc2[i][j] = __builtin_amdgcn_mfma_f32_16x16x32_bf16(a2[i], b2[j], acc2[i][j], 0, 0, 0);
        }

#pragma unroll
        for (int j = 0; j < 3; ++j) {
            int col = j * 16 + l16;
            if (col >= OUT_DIM) continue;
            float bj = bout[col];
#pragma unroll
            for (int i = 0; i < 2; ++i) {
                int grB = rowBase + wv * 32 + i * 16 + q * 4;
#pragma unroll
                for (int r = 0; r < 4; ++r) {
                    int gr = grB + r;
                    if (gr < M) out[(size_t)gr * OUT_DIM + col] = acc2[i][j][r] + bj;
                }
            }
        }
    }
}

// ---------------------------------------------------------------------------
// CSR build (once per launch; edge structure is iteration-invariant)
// ---------------------------------------------------------------------------
__global__ __launch_bounds__(256) void hist_kernel(const int* __restrict__ dst,
                                                   int* __restrict__ cnt) {
    int e = blockIdx.x * 256 + threadIdx.x;
    if (e < E_EDGES) atomicAdd(&cnt[dst[e]], 1);
}

__global__ __launch_bounds__(256) void scan_phase1(const int* __restrict__ deg,
                                                   int* __restrict__ localEx,
                                                   int* __restrict__ blockSums) {
    __shared__ int tmp[256];
    const int t = threadIdx.x;
    const int i = blockIdx.x * 256 + t;
    int v = (i < N_NODES) ? deg[i] : 0;
    tmp[t] = v;
    __syncthreads();
#pragma unroll
    for (int off = 1; off < 256; off <<= 1) {
        int u = (t >= off) ? tmp[t - off] : 0;
        __syncthreads();
        tmp[t] += u;
        __syncthreads();
    }
    if (i < N_NODES) localEx[i] = tmp[t] - v;
    if (t == 255) blockSums[blockIdx.x] = tmp[255];
}

// merged phase2+3: every block redundantly scans the 196 block sums (read-only),
// picks its own exclusive offset, finalizes rowStart + cursor.
__global__ __launch_bounds__(256) void scan_phase23(int* __restrict__ rowStart,
                                                    const int* __restrict__ blockSums,
                                                    int* __restrict__ cursor) {
    __shared__ int tmp[256];
    __shared__ int offs;
    const int t = threadIdx.x;
    int v = (t < SCAN_BLOCKS) ? blockSums[t] : 0;
    tmp[t] = v;
    __syncthreads();
#pragma unroll
    for (int off = 1; off < 256; off <<= 1) {
        int u = (t >= off) ? tmp[t - off] : 0;
        __syncthreads();
        tmp[t] += u;
        __syncthreads();
    }
    if (t == blockIdx.x) offs = tmp[t] - v;
    __syncthreads();
    const int i = blockIdx.x * 256 + t;
    if (i < N_NODES) {
        int val = rowStart[i] + offs;
        rowStart[i] = val;
        cursor[i] = val;
    }
}

// ---------------------------------------------------------------------------
// Gather raw x: aggxh[n] = bf16( sum_e w_e * xh[src_e] )
// 16 lanes/node (16 B/lane), unroll-4 -> 16 independent load chains/wave.
// ---------------------------------------------------------------------------
__global__ __launch_bounds__(256) void gather_x_kernel(
        const ushort* __restrict__ xh, const int2* __restrict__ es2,
        const int* __restrict__ rowStart, const int* __restrict__ rowEnd,
        ushort* __restrict__ aggxh) {
    int gid = blockIdx.x * 256 + threadIdx.x;
    int node = gid >> 4;
    if (node >= N_NODES) return;
    int q = gid & 15;                     // elems [q*8, q*8+8)
    int e = rowStart[node], end = rowEnd[node];

    float sA[8] = {0,0,0,0,0,0,0,0};
    float sB[8] = {0,0,0,0,0,0,0,0};
    for (; e + 4 <= end; e += 4) {
        int2 m0 = es2[e], m1 = es2[e + 1], m2 = es2[e + 2], m3 = es2[e + 3];
        uint4 v0 = *(const uint4*)(xh + (size_t)m0.x * 128 + q * 8);
        uint4 v1 = *(const uint4*)(xh + (size_t)m1.x * 128 + q * 8);
        uint4 v2 = *(const uint4*)(xh + (size_t)m2.x * 128 + q * 8);
        uint4 v3 = *(const uint4*)(xh + (size_t)m3.x * 128 + q * 8);
        float w0 = __int_as_float(m0.y), w1 = __int_as_float(m1.y);
        float w2 = __int_as_float(m2.y), w3 = __int_as_float(m3.y);
        sA[0] = fmaf(w0, bflo(v0.x), sA[0]); sA[1] = fmaf(w0, bfhi(v0.x), sA[1]);
        sA[2] = fmaf(w0, bflo(v0.y), sA[2]); sA[3] = fmaf(w0, bfhi(v0.y), sA[3]);
        sA[4] = fmaf(w0, bflo(v0.z), sA[4]); sA[5] = fmaf(w0, bfhi(v0.z), sA[5]);
        sA[6] = fmaf(w0, bflo(v0.w), sA[6]); sA[7] = fmaf(w0, bfhi(v0.w), sA[7]);
        sB[0] = fmaf(w1, bflo(v1.x), sB[0]); sB[1] = fmaf(w1, bfhi(v1.x), sB[1]);
        sB[2] = fmaf(w1, bflo(v1.y), sB[2]); sB[3] = fmaf(w1, bfhi(v1.y), sB[3]);
        sB[4] = fmaf(w1, bflo(v1.z), sB[4]); sB[5] = fmaf(w1, bfhi(v1.z), sB[5]);
        sB[6] = fmaf(w1, bflo(v1.w), sB[6]); sB[7] = fmaf(w1, bfhi(v1.w), sB[7]);
        sA[0] = fmaf(w2, bflo(v2.x), sA[0]); sA[1] = fmaf(w2, bfhi(v2.x), sA[1]);
        sA[2] = fmaf(w2, bflo(v2.y), sA[2]); sA[3] = fmaf(w2, bfhi(v2.y), sA[3]);
        sA[4] = fmaf(w2, bflo(v2.z), sA[4]); sA[5] = fmaf(w2, bfhi(v2.z), sA[5]);
        sA[6] = fmaf(w2, bflo(v2.w), sA[6]); sA[7] = fmaf(w2, bfhi(v2.w), sA[7]);
        sB[0] = fmaf(w3, bflo(v3.x), sB[0]); sB[1] = fmaf(w3, bfhi(v3.x), sB[1]);
        sB[2] = fmaf(w3, bflo(v3.y), sB[2]); sB[3] = fmaf(w3, bfhi(v3.y), sB[3]);
        sB[4] = fmaf(w3, bflo(v3.z), sB[4]); sB[5] = fmaf(w3, bfhi(v3.z), sB[5]);
        sB[6] = fmaf(w3, bflo(v3.w), sB[6]); sB[7] = fmaf(w3, bfhi(v3.w), sB[7]);
    }
    for (; e < end; ++e) {
        int2 m = es2[e];
        float w = __int_as_float(m.y);
        uint4 v = *(const uint4*)(xh + (size_t)m.x * 128 + q * 8);
        sA[0] = fmaf(w, bflo(v.x), sA[0]); sA[1] = fmaf(w, bfhi(v.x), sA[1]);
        sA[2] = fmaf(w, bflo(v.y), sA[2]); sA[3] = fmaf(w, bfhi(v.y), sA[3]);
        sA[4] = fmaf(w, bflo(v.z), sA[4]); sA[5] = fmaf(w, bfhi(v.z), sA[5]);
        sA[6] = fmaf(w, bflo(v.w), sA[6]); sA[7] = fmaf(w, bfhi(v.w), sA[7]);
    }
    uint4 o;
    o.x = (uint)f2bf(sA[0] + sB[0]) | ((uint)f2bf(sA[1] + sB[1]) << 16);
    o.y = (uint)f2bf(sA[2] + sB[2]) | ((uint)f2bf(sA[3] + sB[3]) << 16);
    o.z = (uint)f2bf(sA[4] + sB[4]) | ((uint)f2bf(sA[5] + sB[5]) << 16);
    o.w = (uint)f2bf(sA[6] + sB[6]) | ((uint)f2bf(sA[7] + sB[7]) << 16);
    *(uint4*)(aggxh + (size_t)node * 128 + q * 8) = o;
}

extern "C" void kernel_launch(void* const* d_in, const int* in_sizes, int n_in,
                              void* d_out, int out_size, void* d_ws, size_t ws_size,
                              hipStream_t stream) {
    const float* x_in   = (const float*)d_in[0];
    const int*   ei     = (const int*)  d_in[1];   // (2,E) int32: src=ei, dst=ei+E
    const float* ew     = (const float*)d_in[2];
    const float* W_emb  = (const float*)d_in[3];
    const float* b_emb  = (const float*)d_in[4];
    const float* W_lin  = (const float*)d_in[5];
    const float* W_anti = (const float*)d_in[6];
    const float* b_conv = (const float*)d_in[7];
    const float* W_out  = (const float*)d_in[8];
    const float* b_out  = (const float*)d_in[9];
    float* out = (float*)d_out;

    // workspace: xh(bf16) | aggxh(bf16) | WembH | Wcat2H | WoutH |
    //            rowStart | cursor | es2(int2) | blockSums    (~31 MB)
    ushort* xh     = (ushort*)d_ws;
    ushort* aggxh  = xh + (size_t)N_NODES * D_DIM;
    ushort* WembH  = aggxh + (size_t)N_NODES * D_DIM;
    ushort* Wcat2H = WembH + D_DIM * D_DIM;
    ushort* WoutH  = Wcat2H + 2 * D_DIM * D_DIM;
    int*    rowStart = (int*)(WoutH + 48 * D_DIM);
    int*    cursor   = rowStart + N_NODES;
    int2*   es2      = (int2*)(cursor + N_NODES);
    int*    blockSums = (int*)(es2 + E_EDGES);

    const int* src = ei;
    const int* dst = ei + E_EDGES;

    // ---- CSR chain + weight prep ----
    zero_prep_kernel<<<SCAN_BLOCKS, 256, 0, stream>>>(cursor, W_emb, W_lin, W_anti,
                                                      W_out, WembH, Wcat2H, WoutH);
    hist_kernel<<<EDGE_BLOCKS, 256, 0, stream>>>(dst, cursor);
    scan_phase1<<<SCAN_BLOCKS, 256, 0, stream>>>(cursor, rowStart, blockSums);
    scan_phase23<<<SCAN_BLOCKS, 256, 0, stream>>>(rowStart, blockSums, cursor);
    // ---- build (CSR scatter) + embed GEMM, role-split & overlapped ----
    build_embed_kernel<<<GEMM_BLOCKS + EDGE_BLOCKS, 256, 0, stream>>>(
        x_in, WembH, b_emb, xh, src, dst, ew, cursor, es2, N_NODES);
    // after build: cursor[d] == row end offset

    // ---- iterations: gather + conv GEMM (bf16 in-place state); last conv
    //      fuses the readout ----
    for (int it = 0; it < N_ITERS; ++it) {
        gather_x_kernel<<<(N_NODES * 16 + 255) / 256, 256, 0, stream>>>(
            xh, es2, rowStart, cursor, aggxh);
        mfma_conv_update<<<GEMM_BLOCKS, 256, 0, stream>>>(
            xh, aggxh, Wcat2H, b_conv, WoutH, b_out, out,
            (it == N_ITERS - 1) ? 1 : 0, N_NODES);
    }
}